// Round 4
// baseline (173.239 us; speedup 1.0000x reference)
//
#include <hip/hip_runtime.h>
#include <math.h>

#define HID 128
#define NPOS 80
#define RPB 8      // batch rows per block; 1 row per wave, 8 waves (512 thr)

__device__ __forceinline__ float elu(float x) {
    return x > 0.f ? x : (expf(x) - 1.f);
}

__device__ __forceinline__ ushort f2bf_rne(float x) {
    unsigned int u = __float_as_uint(x);
    return (ushort)((u + 0x7fffu + ((u >> 16) & 1u)) >> 16);
}

// W1 fp32 -> bf16 (RNE), 4 elements/thread, fully coalesced.
__global__ __launch_bounds__(256) void conv_w1(const float* __restrict__ W1,
                                               ushort* __restrict__ W1b, int n4) {
    int i = blockIdx.x * 256 + threadIdx.x;
    if (i < n4) {
        float4 f = ((const float4*)W1)[i];
        ushort4 u;
        u.x = f2bf_rne(f.x); u.y = f2bf_rne(f.y);
        u.z = f2bf_rne(f.z); u.w = f2bf_rne(f.w);
        ((ushort4*)W1b)[i] = u;
    }
}

template<int BF16>
__global__ __launch_bounds__(512) void tle_main(
    const int* __restrict__ msg, const void* __restrict__ W1v,
    const float* __restrict__ b1,
    const float* __restrict__ W2, const float* __restrict__ b2,
    const float* __restrict__ W3, const float* __restrict__ b3,
    const float* __restrict__ W4, const float* __restrict__ b4,
    float* __restrict__ out)
{
    const int tid  = threadIdx.x;
    const int lane = tid & 63;
    const int w    = tid >> 6;        // 0..7: wave id = private batch row
    const int jj   = lane << 1;       // hidden pair [jj, jj+1]
    const int b0   = blockIdx.x * RPB;

    __shared__ int   smsg[RPB * NPOS];   // 2.5 KB
    __shared__ float sh[RPB][HID];       // 4 KB

    for (int k = tid; k < RPB * NPOS; k += 512)
        smsg[k] = msg[b0 * NPOS + k];
    __syncthreads();   // only barrier in the kernel

    const int* m = &smsg[w * NPOS];

    // ---- Layer 1: gather-sum of W1 rows; 8 loads in flight, 256B/wave ----
    float hx = b1[jj], hy = b1[jj + 1];
    #pragma unroll 1
    for (int p0 = 0; p0 < NPOS; p0 += 8) {
        int c[8];
        #pragma unroll
        for (int u = 0; u < 8; ++u) c[u] = m[p0 + u];    // LDS broadcast
        if (BF16) {
            const ushort* W1b = (const ushort*)W1v;
            unsigned int v[8];
            #pragma unroll
            for (int u = 0; u < 8; ++u)
                v[u] = *(const unsigned int*)(W1b + (((p0 + u) << 15) + (c[u] << 7) + jj));
            #pragma unroll
            for (int u = 0; u < 8; ++u) {
                hx += __uint_as_float(v[u] << 16);            // element jj
                hy += __uint_as_float(v[u] & 0xffff0000u);    // element jj+1
            }
        } else {
            const float* W1f = (const float*)W1v;
            float2 v[8];
            #pragma unroll
            for (int u = 0; u < 8; ++u)
                v[u] = *(const float2*)&W1f[(((p0 + u) << 15) + (c[u] << 7) + jj)];
            #pragma unroll
            for (int u = 0; u < 8; ++u) { hx += v[u].x; hy += v[u].y; }
        }
    }
    // Wave-private row of sh: no cross-wave sync needed anywhere below.
    sh[w][jj]     = elu(hx);
    sh[w][jj + 1] = elu(hy);

    // ---- Dense layers 2..4: wave-local matvec, barrier-free ----
    const float* Ws[3] = { W2, W3, W4 };
    const float* bs[3] = { b2, b3, b4 };
    #pragma unroll 1
    for (int L = 0; L < 3; ++L) {
        const float* __restrict__ W = Ws[L];
        float ax = bs[L][jj], ay = bs[L][jj + 1];
        #pragma unroll 1
        for (int i0 = 0; i0 < HID; i0 += 8) {
            float4 xa = *(const float4*)&sh[w][i0];       // wave-uniform broadcast
            float4 xb = *(const float4*)&sh[w][i0 + 4];
            float2 wv[8];
            #pragma unroll
            for (int u = 0; u < 8; ++u)
                wv[u] = *(const float2*)&W[(i0 + u) * HID + jj];
            ax += xa.x * wv[0].x; ay += xa.x * wv[0].y;
            ax += xa.y * wv[1].x; ay += xa.y * wv[1].y;
            ax += xa.z * wv[2].x; ay += xa.z * wv[2].y;
            ax += xa.w * wv[3].x; ay += xa.w * wv[3].y;
            ax += xb.x * wv[4].x; ay += xb.x * wv[4].y;
            ax += xb.y * wv[5].x; ay += xb.y * wv[5].y;
            ax += xb.z * wv[6].x; ay += xb.z * wv[6].y;
            ax += xb.w * wv[7].x; ay += xb.w * wv[7].y;
        }
        sh[w][jj]     = elu(ax);
        sh[w][jj + 1] = elu(ay);
    }

    *(float2*)&out[(b0 + w) * HID + jj] =
        make_float2(sh[w][jj], sh[w][jj + 1]);
}

extern "C" void kernel_launch(void* const* d_in, const int* in_sizes, int n_in,
                              void* d_out, int out_size, void* d_ws, size_t ws_size,
                              hipStream_t stream) {
    const int*   msg = (const int*)  d_in[0];
    const float* W1  = (const float*)d_in[1];
    const float* b1  = (const float*)d_in[2];
    const float* W2  = (const float*)d_in[3];
    const float* b2  = (const float*)d_in[4];
    const float* W3  = (const float*)d_in[5];
    const float* b3  = (const float*)d_in[6];
    const float* W4  = (const float*)d_in[7];
    const float* b4  = (const float*)d_in[8];
    float* out = (float*)d_out;

    const int B = in_sizes[0] / NPOS;            // 8192
    const int n_w1 = NPOS * 256 * HID;           // 2,621,440 floats
    const size_t need = (size_t)n_w1 * sizeof(ushort);   // 5.25 MB

    dim3 grid(B / RPB), block(512);
    if (ws_size >= need) {
        ushort* W1b = (ushort*)d_ws;
        const int n4 = n_w1 / 4;
        conv_w1<<<dim3((n4 + 255) / 256), dim3(256), 0, stream>>>(W1, W1b, n4);
        tle_main<1><<<grid, block, 0, stream>>>(msg, (const void*)W1b, b1,
                                                W2, b2, W3, b3, W4, b4, out);
    } else {
        tle_main<0><<<grid, block, 0, stream>>>(msg, (const void*)W1, b1,
                                                W2, b2, W3, b3, W4, b4, out);
    }
}

// Round 5
// 113.281 us; speedup vs baseline: 1.5293x; 1.5293x over previous
//
#include <hip/hip_runtime.h>
#include <math.h>

#define HID   128
#define NPOS  80
#define RPB   16          // rows per block: 4 waves x 4 rows
#define XSTR  132         // padded X row stride (floats)

typedef float  f4   __attribute__((ext_vector_type(4)));
typedef unsigned int u32x4 __attribute__((ext_vector_type(4)));
typedef int    i32x4 __attribute__((ext_vector_type(4)));

__device__ __forceinline__ float elu(float x) {
    return x > 0.f ? x : (expf(x) - 1.f);
}
__device__ __forceinline__ f4 elu4(f4 v) {
    f4 r; r.x = elu(v.x); r.y = elu(v.y); r.z = elu(v.z); r.w = elu(v.w);
    return r;
}
__device__ __forceinline__ float bflo(unsigned int u) { return __uint_as_float(u << 16); }
__device__ __forceinline__ float bfhi(unsigned int u) { return __uint_as_float(u & 0xffff0000u); }

__device__ __forceinline__ unsigned short f2bf_rne(float x) {
    unsigned int u = __float_as_uint(x);
    return (unsigned short)((u + 0x7fffu + ((u >> 16) & 1u)) >> 16);
}

// W1 fp32 -> bf16 (RNE), coalesced.
__global__ __launch_bounds__(256) void conv_w1(const float* __restrict__ W1,
                                               unsigned short* __restrict__ W1b, int n4) {
    int i = blockIdx.x * 256 + threadIdx.x;
    if (i < n4) {
        f4 f = ((const f4*)W1)[i];
        ushort4 u;
        u.x = f2bf_rne(f.x); u.y = f2bf_rne(f.y);
        u.z = f2bf_rne(f.z); u.w = f2bf_rne(f.w);
        ((ushort4*)W1b)[i] = u;
    }
}

__global__ __launch_bounds__(256) void tle_main(
    const int* __restrict__ msg, const unsigned short* __restrict__ W1b,
    const float* __restrict__ b1,
    const float* __restrict__ W2, const float* __restrict__ b2,
    const float* __restrict__ W3, const float* __restrict__ b3,
    const float* __restrict__ W4, const float* __restrict__ b4,
    float* __restrict__ out)
{
    const int tid  = threadIdx.x;
    const int lane = tid & 63;
    const int w    = tid >> 6;          // 0..3 wave id
    const int r    = lane >> 4;         // 0..3: which row of the wave's 4
    const int s    = lane & 15;         // 16-byte segment within row
    const int b0   = blockIdx.x * RPB;
    const int m    = (w << 2) + r;      // block-local row for gather phase

    __shared__ int   smsg[RPB * NPOS];      // 5 KB
    __shared__ float X[RPB * XSTR];         // 8.25 KB
    __shared__ float Wbuf[HID * HID];       // 64 KB

    for (int k = tid; k < RPB * NPOS; k += 256)
        smsg[k] = msg[b0 * NPOS + k];
    __syncthreads();

    // ---- Layer 1: gather. One dwordx4 = 16B/lane = 4 bf16 rows per wave-request.
    const int soff = s << 3;                        // ushort offset in row
    f4 acc0 = *(const f4*)&b1[soff];                // bias for comps [8s..8s+4)
    f4 acc1 = *(const f4*)&b1[soff + 4];
    const int* mrow = &smsg[m * NPOS];

    #pragma unroll 1
    for (int p0 = 0; p0 < NPOS; p0 += 8) {
        i32x4 ca = *(const i32x4*)&mrow[p0];        // quarter-wave-uniform LDS reads
        i32x4 cb = *(const i32x4*)&mrow[p0 + 4];
        int c[8] = { ca.x, ca.y, ca.z, ca.w, cb.x, cb.y, cb.z, cb.w };
        u32x4 v[8];
        #pragma unroll
        for (int u = 0; u < 8; ++u)
            v[u] = *(const u32x4*)&W1b[((p0 + u) << 15) + (c[u] << 7) + soff];
        #pragma unroll
        for (int u = 0; u < 8; ++u) {
            acc0.x += bflo(v[u].x); acc0.y += bfhi(v[u].x);
            acc0.z += bflo(v[u].y); acc0.w += bfhi(v[u].y);
            acc1.x += bflo(v[u].z); acc1.y += bfhi(v[u].z);
            acc1.z += bflo(v[u].w); acc1.w += bfhi(v[u].w);
        }
    }
    // ELU; X row m is wave-private.
    *(f4*)&X[m * XSTR + soff]     = elu4(acc0);
    *(f4*)&X[m * XSTR + soff + 4] = elu4(acc1);

    // ---- Dense layers: W staged fp32 into LDS, VALU matvec.
    const int j4 = (lane & 31) << 2;     // 4 output cols per lane
    const int rh = lane >> 5;            // half-wave picks row pair
    const int m0 = (w << 2) + (rh << 1);
    const int m1 = m0 + 1;
    const float* Ws[3] = { W2, W3, W4 };
    const float* bs[3] = { b2, b3, b4 };

    #pragma unroll 1
    for (int L = 0; L < 3; ++L) {
        __syncthreads();   // prior-layer Wbuf reads done (no-op for L=0)
        {
            const f4* Wg = (const f4*)Ws[L];
            #pragma unroll
            for (int t = 0; t < (HID * HID / 4) / 256; ++t)
                ((f4*)Wbuf)[tid + t * 256] = Wg[tid + t * 256];
        }
        __syncthreads();   // staging visible

        f4 a0 = *(const f4*)&bs[L][j4];
        f4 a1 = a0;
        #pragma unroll 1
        for (int i0 = 0; i0 < HID; i0 += 4) {
            f4 x0 = *(const f4*)&X[m0 * XSTR + i0];   // half-wave-uniform: broadcast
            f4 x1 = *(const f4*)&X[m1 * XSTR + i0];
            f4 w0 = *(const f4*)&Wbuf[(i0 + 0) * HID + j4];
            f4 w1 = *(const f4*)&Wbuf[(i0 + 1) * HID + j4];
            f4 w2 = *(const f4*)&Wbuf[(i0 + 2) * HID + j4];
            f4 w3 = *(const f4*)&Wbuf[(i0 + 3) * HID + j4];
            a0 += x0.x * w0; a1 += x1.x * w0;
            a0 += x0.y * w1; a1 += x1.y * w1;
            a0 += x0.z * w2; a1 += x1.z * w2;
            a0 += x0.w * w3; a1 += x1.w * w3;
        }
        f4 e0 = elu4(a0), e1 = elu4(a1);
        if (L < 2) {
            *(f4*)&X[m0 * XSTR + j4] = e0;   // wave-private rows
            *(f4*)&X[m1 * XSTR + j4] = e1;
        } else {
            *(f4*)&out[(b0 + m0) * HID + j4] = e0;
            *(f4*)&out[(b0 + m1) * HID + j4] = e1;
        }
    }
}

extern "C" void kernel_launch(void* const* d_in, const int* in_sizes, int n_in,
                              void* d_out, int out_size, void* d_ws, size_t ws_size,
                              hipStream_t stream) {
    const int*   msg = (const int*)  d_in[0];
    const float* W1  = (const float*)d_in[1];
    const float* b1  = (const float*)d_in[2];
    const float* W2  = (const float*)d_in[3];
    const float* b2  = (const float*)d_in[4];
    const float* W3  = (const float*)d_in[5];
    const float* b3  = (const float*)d_in[6];
    const float* W4  = (const float*)d_in[7];
    const float* b4  = (const float*)d_in[8];
    float* out = (float*)d_out;

    const int B = in_sizes[0] / NPOS;            // 8192
    const int n_w1 = NPOS * 256 * HID;           // 2,621,440 elements

    unsigned short* W1b = (unsigned short*)d_ws; // 5.25 MB (ws verified sufficient in R4)
    const int n4 = n_w1 / 4;
    conv_w1<<<dim3((n4 + 255) / 256), dim3(256), 0, stream>>>(W1, W1b, n4);

    dim3 grid(B / RPB), block(256);
    tle_main<<<grid, block, 0, stream>>>(msg, W1b, b1, W2, b2, W3, b3, W4, b4, out);
}

// Round 7
// 107.437 us; speedup vs baseline: 1.6125x; 1.0544x over previous
//
#include <hip/hip_runtime.h>
#include <math.h>

#define HID  128
#define NPOS 80
#define XS   136   // padded LDS X stride (bf16 elems): 272B rows -> 2-way-free banks

typedef float f4 __attribute__((ext_vector_type(4)));
typedef int   i4 __attribute__((ext_vector_type(4)));
typedef unsigned int u32;
typedef __attribute__((ext_vector_type(8))) short bf16x8;   // 8 bf16 (guide-blessed)
typedef __attribute__((ext_vector_type(4))) float f32x4;

__device__ __forceinline__ float elu(float x) { return x > 0.f ? x : (expf(x) - 1.f); }
__device__ __forceinline__ unsigned short f2bf(float x) {
    u32 u = __float_as_uint(x);
    return (unsigned short)((u + 0x7fffu + ((u >> 16) & 1u)) >> 16);
}
__device__ __forceinline__ float bf2f(unsigned short h) { return __uint_as_float(((u32)h) << 16); }
__device__ __forceinline__ float bflo(u32 v) { return __uint_as_float(v << 16); }
__device__ __forceinline__ float bfhi(u32 v) { return __uint_as_float(v & 0xffff0000u); }

// ---- prep: W1 -> bf16; W2/3/4 -> transposed [n][k] bf16 hi/lo pairs ----
// W1: 2,621,440 floats = 655,360 f4 groups -> 2560 blocks (R6 bug: had 640).
#define W1_BLOCKS 2560
__global__ __launch_bounds__(256) void prep(
    const float* __restrict__ W1, const float* __restrict__ W2,
    const float* __restrict__ W3, const float* __restrict__ W4,
    unsigned short* __restrict__ W1b,
    unsigned short* __restrict__ WtH, unsigned short* __restrict__ WtL)
{
    int b = blockIdx.x;
    if (b < W1_BLOCKS) {
        int i = b * 256 + threadIdx.x;               // f4-group index, < 655360
        f4 f = ((const f4*)W1)[i];
        ushort4 u4;
        u4.x = f2bf(f.x); u4.y = f2bf(f.y); u4.z = f2bf(f.z); u4.w = f2bf(f.w);
        ((ushort4*)W1b)[i] = u4;
    } else {                             // 3 x 128 x 128 = 49152 elems / 256 = 192 blocks
        int t = (b - W1_BLOCKS) * 256 + threadIdx.x; // t = L*16384 + n*128 + k
        int L = t >> 14;
        int nk = t & 16383;
        int n = nk >> 7, k = nk & 127;
        const float* W = (L == 0) ? W2 : (L == 1) ? W3 : W4;
        float w = W[k * HID + n];                    // transpose read (small, L2-hot)
        unsigned short hi = f2bf(w);
        WtH[t] = hi;
        WtL[t] = f2bf(w - bf2f(hi));
    }
}

// ---- gather: 1 row per wave, 16 x 256B loads in flight, writes H into out ----
__global__ __launch_bounds__(256) void gather_k(
    const int* __restrict__ msg, const unsigned short* __restrict__ W1b,
    const float* __restrict__ b1, float* __restrict__ H)
{
    const int tid = threadIdx.x, lane = tid & 63, w = tid >> 6;
    const int row = blockIdx.x * 4 + w;

    __shared__ int smsg[4 * NPOS];       // 1.25 KB
    for (int k = tid; k < 4 * NPOS; k += 256)
        smsg[k] = msg[blockIdx.x * 4 * NPOS + k];
    __syncthreads();

    const int* mrow = &smsg[w * NPOS];
    const int loff = lane << 1;          // hidden pair [2*lane, 2*lane+1]
    float2 bv = *(const float2*)&b1[loff];
    float hx = bv.x, hy = bv.y;

    #pragma unroll 1
    for (int p0 = 0; p0 < NPOS; p0 += 16) {
        i4 ca = *(const i4*)&mrow[p0];
        i4 cb = *(const i4*)&mrow[p0 + 4];
        i4 cc = *(const i4*)&mrow[p0 + 8];
        i4 cd = *(const i4*)&mrow[p0 + 12];
        int c[16] = { ca.x, ca.y, ca.z, ca.w, cb.x, cb.y, cb.z, cb.w,
                      cc.x, cc.y, cc.z, cc.w, cd.x, cd.y, cd.z, cd.w };
        u32 v[16];
        #pragma unroll
        for (int u = 0; u < 16; ++u)
            v[u] = *(const u32*)(W1b + (((p0 + u) << 15) + (c[u] << 7) + loff));
        #pragma unroll
        for (int u = 0; u < 16; ++u) { hx += bflo(v[u]); hy += bfhi(v[u]); }
    }
    *(float2*)&H[row * HID + loff] = make_float2(elu(hx), elu(hy));
}

// ---- dense: 16 rows/block, MFMA 16x16x32 bf16, 3-pass hi/lo split, in-place on out ----
__global__ __launch_bounds__(256) void dense_k(
    const unsigned short* __restrict__ WtH, const unsigned short* __restrict__ WtL,
    const float* __restrict__ b2, const float* __restrict__ b3,
    const float* __restrict__ b4, float* __restrict__ H)
{
    const int tid = threadIdx.x, lane = tid & 63, w = tid >> 6;
    const int quad = lane >> 4, l15 = lane & 15;
    const int r0 = blockIdx.x * 16;

    __shared__ unsigned short Xh[16 * XS];   // 4.25 KB
    __shared__ unsigned short Xl[16 * XS];   // 4.25 KB

    // Stage H -> bf16 hi/lo (8 elems per thread)
    {
        const int m = tid >> 4, k0 = (tid & 15) << 3;
        f4 a = *(const f4*)&H[(r0 + m) * HID + k0];
        f4 b = *(const f4*)&H[(r0 + m) * HID + k0 + 4];
        float xs[8] = { a.x, a.y, a.z, a.w, b.x, b.y, b.z, b.w };
        unsigned short hs[8], ls[8];
        #pragma unroll
        for (int u = 0; u < 8; ++u) {
            hs[u] = f2bf(xs[u]);
            ls[u] = f2bf(xs[u] - bf2f(hs[u]));
        }
        *(ushort4*)&Xh[m * XS + k0]     = make_ushort4(hs[0], hs[1], hs[2], hs[3]);
        *(ushort4*)&Xh[m * XS + k0 + 4] = make_ushort4(hs[4], hs[5], hs[6], hs[7]);
        *(ushort4*)&Xl[m * XS + k0]     = make_ushort4(ls[0], ls[1], ls[2], ls[3]);
        *(ushort4*)&Xl[m * XS + k0 + 4] = make_ushort4(ls[4], ls[5], ls[6], ls[7]);
    }
    __syncthreads();

    const float* bs[3] = { b2, b3, b4 };

    #pragma unroll 1
    for (int L = 0; L < 3; ++L) {
        // A-frags: A[m=lane&15][k=quad*8+j]  (m120-verified layout)
        bf16x8 Ah[4], Al[4];
        #pragma unroll
        for (int kt = 0; kt < 4; ++kt) {
            const int off = l15 * XS + kt * 32 + quad * 8;
            Ah[kt] = *(const bf16x8*)&Xh[off];
            Al[kt] = *(const bf16x8*)&Xl[off];
        }

        const unsigned short* WH = WtH + L * 16384;
        const unsigned short* WL = WtL + L * 16384;
        f32x4 acc[2] = { {0,0,0,0}, {0,0,0,0} };

        #pragma unroll
        for (int nt = 0; nt < 2; ++nt) {
            const int n = w * 32 + nt * 16 + l15;
            #pragma unroll
            for (int kt = 0; kt < 4; ++kt) {
                const int boff = n * HID + kt * 32 + quad * 8;   // B^T[n][k] contiguous
                bf16x8 Bh = *(const bf16x8*)&WH[boff];
                bf16x8 Bl = *(const bf16x8*)&WL[boff];
                acc[nt] = __builtin_amdgcn_mfma_f32_16x16x32_bf16(Ah[kt], Bh, acc[nt], 0, 0, 0);
                acc[nt] = __builtin_amdgcn_mfma_f32_16x16x32_bf16(Ah[kt], Bl, acc[nt], 0, 0, 0);
                acc[nt] = __builtin_amdgcn_mfma_f32_16x16x32_bf16(Al[kt], Bh, acc[nt], 0, 0, 0);
            }
        }
        __syncthreads();   // all waves' A-frag reads retired before X overwrite

        // Epilogue: C layout col=lane&15, row=quad*4+reg (m89-verified)
        #pragma unroll
        for (int nt = 0; nt < 2; ++nt) {
            const int n = w * 32 + nt * 16 + l15;
            const float bias = bs[L][n];
            #pragma unroll
            for (int r = 0; r < 4; ++r) {
                const int m = quad * 4 + r;
                const float y = elu(acc[nt][r] + bias);
                if (L < 2) {
                    unsigned short hi = f2bf(y);
                    Xh[m * XS + n] = hi;
                    Xl[m * XS + n] = f2bf(y - bf2f(hi));
                } else {
                    H[(r0 + m) * HID + n] = y;
                }
            }
        }
        if (L < 2) __syncthreads();
    }
}

extern "C" void kernel_launch(void* const* d_in, const int* in_sizes, int n_in,
                              void* d_out, int out_size, void* d_ws, size_t ws_size,
                              hipStream_t stream) {
    const int*   msg = (const int*)  d_in[0];
    const float* W1  = (const float*)d_in[1];
    const float* b1  = (const float*)d_in[2];
    const float* W2  = (const float*)d_in[3];
    const float* b2  = (const float*)d_in[4];
    const float* W3  = (const float*)d_in[5];
    const float* b3  = (const float*)d_in[6];
    const float* W4  = (const float*)d_in[7];
    const float* b4  = (const float*)d_in[8];
    float* out = (float*)d_out;

    // ws layout: W1b (2621440 ushorts) | WtH (49152) | WtL (49152) = 5.44 MB
    unsigned short* W1b = (unsigned short*)d_ws;
    unsigned short* WtH = W1b + 2621440;
    unsigned short* WtL = WtH + 49152;

    prep    <<<dim3(W1_BLOCKS + 192), dim3(256), 0, stream>>>(W1, W2, W3, W4, W1b, WtH, WtL);
    gather_k<<<dim3(2048),            dim3(256), 0, stream>>>(msg, W1b, b1, out);
    dense_k <<<dim3(512),             dim3(256), 0, stream>>>(WtH, WtL, b2, b3, b4, out);
}

// Round 8
// 98.069 us; speedup vs baseline: 1.7665x; 1.0955x over previous
//
#include <hip/hip_runtime.h>
#include <math.h>

#define HID  128
#define NPOS 80
#define XS   136   // padded LDS X stride (bf16 elems)

typedef float f4 __attribute__((ext_vector_type(4)));
typedef unsigned int u32;
typedef u32 u32x4 __attribute__((ext_vector_type(4)));
typedef __attribute__((ext_vector_type(8))) short bf16x8;
typedef __attribute__((ext_vector_type(4))) float f32x4;

__device__ __forceinline__ float elu(float x) { return x > 0.f ? x : (expf(x) - 1.f); }
__device__ __forceinline__ unsigned short f2bf(float x) {
    u32 u = __float_as_uint(x);
    return (unsigned short)((u + 0x7fffu + ((u >> 16) & 1u)) >> 16);
}
__device__ __forceinline__ float bf2f(unsigned short h) { return __uint_as_float(((u32)h) << 16); }
__device__ __forceinline__ float bflo(u32 v) { return __uint_as_float(v << 16); }
__device__ __forceinline__ float bfhi(u32 v) { return __uint_as_float(v & 0xffff0000u); }

// ---- prep: W1 -> bf16 (2560 blocks); W2/3/4 -> MFMA-B-frag-ordered hi/lo (24 blocks) ----
#define W1_BLOCKS 2560
#define TR_BLOCKS 24     // 3*4*2*4*64 = 6144 threads
__global__ __launch_bounds__(256) void prep(
    const float* __restrict__ W1, const float* __restrict__ W2,
    const float* __restrict__ W3, const float* __restrict__ W4,
    unsigned short* __restrict__ W1b,
    unsigned short* __restrict__ WtH, unsigned short* __restrict__ WtL)
{
    int b = blockIdx.x;
    if (b < W1_BLOCKS) {
        int i = b * 256 + threadIdx.x;               // f4-group index, < 655360
        f4 f = ((const f4*)W1)[i];
        ushort4 u4;
        u4.x = f2bf(f.x); u4.y = f2bf(f.y); u4.z = f2bf(f.z); u4.w = f2bf(f.w);
        ((ushort4*)W1b)[i] = u4;
    } else {
        // t indexes (L, w, nt, kt, lane); each thread emits 8 j's (contiguous 16B hi + 16B lo)
        int t = (b - W1_BLOCKS) * 256 + threadIdx.x;     // 0..6143
        int lane = t & 63;
        int q = t >> 6;
        int kt = q & 3;  q >>= 2;
        int nt = q & 1;  q >>= 1;
        int w  = q & 3;
        int L  = q >> 2;                                  // 0..2
        const float* W = (L == 0) ? W2 : (L == 1) ? W3 : W4;
        const int n    = w * 32 + nt * 16 + (lane & 15);
        const int quad = lane >> 4;
        unsigned short hs[8], ls[8];
        #pragma unroll
        for (int j = 0; j < 8; ++j) {
            const int k = kt * 32 + quad * 8 + j;
            float v = W[k * HID + n];                     // B[k][n] = W^T read
            hs[j] = f2bf(v);
            ls[j] = f2bf(v - bf2f(hs[j]));
        }
        *(ushort4*)&WtH[t * 8]     = make_ushort4(hs[0], hs[1], hs[2], hs[3]);
        *(ushort4*)&WtH[t * 8 + 4] = make_ushort4(hs[4], hs[5], hs[6], hs[7]);
        *(ushort4*)&WtL[t * 8]     = make_ushort4(ls[0], ls[1], ls[2], ls[3]);
        *(ushort4*)&WtL[t * 8 + 4] = make_ushort4(ls[4], ls[5], ls[6], ls[7]);
    }
}

// ---- fused: gather (4 bf16 rows per dwordx4 request) + MFMA dense, 16 rows/block ----
__global__ __launch_bounds__(256) void main_k(
    const int* __restrict__ msg, const unsigned short* __restrict__ W1b,
    const float* __restrict__ b1,
    const unsigned short* __restrict__ WtH, const unsigned short* __restrict__ WtL,
    const float* __restrict__ b2, const float* __restrict__ b3,
    const float* __restrict__ b4, float* __restrict__ out)
{
    const int tid = threadIdx.x, lane = tid & 63, w = tid >> 6;
    const int quad = lane >> 4, l15 = lane & 15;
    const int m    = w * 4 + quad;          // block-local row (gather phase)
    const int soff = l15 << 3;              // 8-elem hidden slice
    const int r0   = blockIdx.x * 16;

    __shared__ int smsg[16 * NPOS];              // 5 KB
    __shared__ unsigned short Xh[16 * XS];       // 4.25 KB
    __shared__ unsigned short Xl[16 * XS];       // 4.25 KB

    for (int k = tid; k < 16 * NPOS; k += 256)
        smsg[k] = msg[r0 * NPOS + k];
    __syncthreads();

    // ---- gather: one dwordx4 covers 4 rows x 256B ----
    const int* mrow = &smsg[m * NPOS];
    f4 acc0 = *(const f4*)&b1[soff];
    f4 acc1 = *(const f4*)&b1[soff + 4];
    #pragma unroll 1
    for (int p0 = 0; p0 < NPOS; p0 += 8) {
        int c[8];
        #pragma unroll
        for (int u = 0; u < 8; ++u) c[u] = mrow[p0 + u];     // quarter-wave-uniform
        u32x4 v[8];
        #pragma unroll
        for (int u = 0; u < 8; ++u)
            v[u] = *(const u32x4*)&W1b[((p0 + u) << 15) + (c[u] << 7) + soff];
        #pragma unroll
        for (int u = 0; u < 8; ++u) {
            acc0.x += bflo(v[u].x); acc0.y += bfhi(v[u].x);
            acc0.z += bflo(v[u].y); acc0.w += bfhi(v[u].y);
            acc1.x += bflo(v[u].z); acc1.y += bfhi(v[u].z);
            acc1.z += bflo(v[u].w); acc1.w += bfhi(v[u].w);
        }
    }
    {   // ELU + hi/lo split straight into LDS
        float xs[8] = { acc0.x, acc0.y, acc0.z, acc0.w, acc1.x, acc1.y, acc1.z, acc1.w };
        unsigned short hs[8], ls[8];
        #pragma unroll
        for (int u = 0; u < 8; ++u) {
            float y = elu(xs[u]);
            hs[u] = f2bf(y);
            ls[u] = f2bf(y - bf2f(hs[u]));
        }
        *(ushort4*)&Xh[m * XS + soff]     = make_ushort4(hs[0], hs[1], hs[2], hs[3]);
        *(ushort4*)&Xh[m * XS + soff + 4] = make_ushort4(hs[4], hs[5], hs[6], hs[7]);
        *(ushort4*)&Xl[m * XS + soff]     = make_ushort4(ls[0], ls[1], ls[2], ls[3]);
        *(ushort4*)&Xl[m * XS + soff + 4] = make_ushort4(ls[4], ls[5], ls[6], ls[7]);
    }
    __syncthreads();

    // ---- dense: MFMA 16x16x32, 3-pass hi/lo split ----
    const float* bs[3] = { b2, b3, b4 };
    #pragma unroll 1
    for (int L = 0; L < 3; ++L) {
        bf16x8 Ah[4], Al[4];
        #pragma unroll
        for (int kt = 0; kt < 4; ++kt) {
            const int off = l15 * XS + kt * 32 + quad * 8;
            Ah[kt] = *(const bf16x8*)&Xh[off];
            Al[kt] = *(const bf16x8*)&Xl[off];
        }
        const unsigned short* WH = WtH + L * 16384;
        const unsigned short* WL = WtL + L * 16384;
        f32x4 acc[2] = { {0,0,0,0}, {0,0,0,0} };
        #pragma unroll
        for (int nt = 0; nt < 2; ++nt) {
            #pragma unroll
            for (int kt = 0; kt < 4; ++kt) {
                const int boff = ((((w << 1) + nt) << 2) + kt) * 512 + lane * 8;  // contiguous 1KB/wave
                bf16x8 Bh = *(const bf16x8*)&WH[boff];
                bf16x8 Bl = *(const bf16x8*)&WL[boff];
                acc[nt] = __builtin_amdgcn_mfma_f32_16x16x32_bf16(Ah[kt], Bh, acc[nt], 0, 0, 0);
                acc[nt] = __builtin_amdgcn_mfma_f32_16x16x32_bf16(Ah[kt], Bl, acc[nt], 0, 0, 0);
                acc[nt] = __builtin_amdgcn_mfma_f32_16x16x32_bf16(Al[kt], Bh, acc[nt], 0, 0, 0);
            }
        }
        __syncthreads();   // A-frag reads retired before X overwrite

        #pragma unroll
        for (int nt = 0; nt < 2; ++nt) {
            const int n = w * 32 + nt * 16 + l15;
            const float bias = bs[L][n];
            #pragma unroll
            for (int r = 0; r < 4; ++r) {
                const int mm = quad * 4 + r;              // C layout: col=l15, row=quad*4+reg
                const float y = elu(acc[nt][r] + bias);
                if (L < 2) {
                    unsigned short hi = f2bf(y);
                    Xh[mm * XS + n] = hi;
                    Xl[mm * XS + n] = f2bf(y - bf2f(hi));
                } else {
                    out[(r0 + mm) * HID + n] = y;
                }
            }
        }
        if (L < 2) __syncthreads();
    }
}

extern "C" void kernel_launch(void* const* d_in, const int* in_sizes, int n_in,
                              void* d_out, int out_size, void* d_ws, size_t ws_size,
                              hipStream_t stream) {
    const int*   msg = (const int*)  d_in[0];
    const float* W1  = (const float*)d_in[1];
    const float* b1  = (const float*)d_in[2];
    const float* W2  = (const float*)d_in[3];
    const float* b2  = (const float*)d_in[4];
    const float* W3  = (const float*)d_in[5];
    const float* b3  = (const float*)d_in[6];
    const float* W4  = (const float*)d_in[7];
    const float* b4  = (const float*)d_in[8];
    float* out = (float*)d_out;

    // ws layout: W1b (2,621,440 ushorts) | WtH (49,152) | WtL (49,152)
    unsigned short* W1b = (unsigned short*)d_ws;
    unsigned short* WtH = W1b + 2621440;
    unsigned short* WtL = WtH + 49152;

    prep  <<<dim3(W1_BLOCKS + TR_BLOCKS), dim3(256), 0, stream>>>(W1, W2, W3, W4, W1b, WtH, WtL);
    main_k<<<dim3(512),                   dim3(256), 0, stream>>>(msg, W1b, b1, WtH, WtL,
                                                                  b2, b3, b4, out);
}

// Round 9
// 96.618 us; speedup vs baseline: 1.7930x; 1.0150x over previous
//
#include <hip/hip_runtime.h>
#include <math.h>

#define HID  128
#define NPOS 80
#define XS   136   // padded LDS X stride (bf16 elems)

typedef float f4 __attribute__((ext_vector_type(4)));
typedef float f2 __attribute__((ext_vector_type(2)));
typedef unsigned int u32;
typedef u32 u32x4 __attribute__((ext_vector_type(4)));
typedef __attribute__((ext_vector_type(8))) short bf16x8;
typedef __attribute__((ext_vector_type(4))) float f32x4;

__device__ __forceinline__ float elu(float x) { return x > 0.f ? x : (expf(x) - 1.f); }
__device__ __forceinline__ unsigned short f2bf(float x) {
    u32 u = __float_as_uint(x);
    return (unsigned short)((u + 0x7fffu + ((u >> 16) & 1u)) >> 16);
}
__device__ __forceinline__ float bf2f(unsigned short h) { return __uint_as_float(((u32)h) << 16); }

// ---- fp8 e4m3fn: software RNE encode (prep-side) ----
__device__ __forceinline__ u32 f2e4m3(float x) {
    u32 u = __float_as_uint(x);
    u32 sign = (u >> 31) << 7;
    float a = fabsf(x);
    if (a >= 448.f) return sign | 0x7e;
    int e = (int)((u >> 23) & 0xff) - 127;
    if (e < -6) {                       // denormal: step 2^-9, RNE
        int q = (int)rintf(a * 512.0f);
        if (q >= 8) return sign | 0x08;
        return sign | (u32)q;
    }
    u32 sig = (u & 0x7fffffu) | 0x800000u;
    u32 rs = sig + 0x7ffffu + ((sig >> 20) & 1u);
    if (rs >= 0x1000000u) { e += 1; rs >>= 1; }
    u32 m3 = (rs >> 20) & 7u;
    u32 enc = ((u32)(e + 7) << 3) | m3;
    if (enc >= 0x7fu) return sign | 0x7e;
    return sign | enc;
}

// ---- fp8 decode: HW packed convert if available, exact SW fallback ----
#if defined(__has_builtin)
#if __has_builtin(__builtin_amdgcn_cvt_pk_f32_fp8)
#define HW_FP8 1
#endif
#endif

#ifdef HW_FP8
__device__ __forceinline__ void dec4_acc(u32 v, f4* A) {
    f2 lo = __builtin_amdgcn_cvt_pk_f32_fp8((int)v, false);   // bytes 0,1
    f2 hi = __builtin_amdgcn_cvt_pk_f32_fp8((int)v, true);    // bytes 2,3
    (*A).x += lo.x; (*A).y += lo.y; (*A).z += hi.x; (*A).w += hi.y;
}
#else
__device__ __forceinline__ float dec1(u32 b) {
    int em = (int)(b & 0x7fu);
    int isn = (em >= 8) ? 1 : 0;
    int frac = (em & 7) | (isn << 3);
    int e2 = isn ? (em >> 3) : 1;
    float f = ldexpf((float)frac, e2 - 10);
    return (b & 0x80u) ? -f : f;
}
__device__ __forceinline__ void dec4_acc(u32 v, f4* A) {
    (*A).x += dec1(v & 0xff); (*A).y += dec1((v >> 8) & 0xff);
    (*A).z += dec1((v >> 16) & 0xff); (*A).w += dec1(v >> 24);
}
#endif

// ---- prep: W1 -> fp8(x64) [2560 blocks]; W2/3/4 -> B-frag-ordered bf16 hi/lo [24 blocks] ----
#define W1_BLOCKS 2560
#define TR_BLOCKS 24
__global__ __launch_bounds__(256) void prep(
    const float* __restrict__ W1, const float* __restrict__ W2,
    const float* __restrict__ W3, const float* __restrict__ W4,
    u32* __restrict__ W1f8,
    unsigned short* __restrict__ WtH, unsigned short* __restrict__ WtL)
{
    int b = blockIdx.x;
    if (b < W1_BLOCKS) {
        int i = b * 256 + threadIdx.x;               // f4-group index, < 655360
        f4 f = ((const f4*)W1)[i];
        u32 pk = f2e4m3(f.x * 64.f)
               | (f2e4m3(f.y * 64.f) << 8)
               | (f2e4m3(f.z * 64.f) << 16)
               | (f2e4m3(f.w * 64.f) << 24);
        W1f8[i] = pk;
    } else {
        int t = (b - W1_BLOCKS) * 256 + threadIdx.x;     // 0..6143
        int lane = t & 63;
        int q = t >> 6;
        int kt = q & 3;  q >>= 2;
        int nt = q & 1;  q >>= 1;
        int w  = q & 3;
        int L  = q >> 2;
        const float* W = (L == 0) ? W2 : (L == 1) ? W3 : W4;
        const int n    = w * 32 + nt * 16 + (lane & 15);
        const int quad = lane >> 4;
        unsigned short hs[8], ls[8];
        #pragma unroll
        for (int j = 0; j < 8; ++j) {
            const int k = kt * 32 + quad * 8 + j;
            float v = W[k * HID + n];
            hs[j] = f2bf(v);
            ls[j] = f2bf(v - bf2f(hs[j]));
        }
        *(ushort4*)&WtH[t * 8]     = make_ushort4(hs[0], hs[1], hs[2], hs[3]);
        *(ushort4*)&WtH[t * 8 + 4] = make_ushort4(hs[4], hs[5], hs[6], hs[7]);
        *(ushort4*)&WtL[t * 8]     = make_ushort4(ls[0], ls[1], ls[2], ls[3]);
        *(ushort4*)&WtL[t * 8 + 4] = make_ushort4(ls[4], ls[5], ls[6], ls[7]);
    }
}

// ---- fused: fp8 gather (8 rows per dwordx4, p-split halves) + MFMA dense ----
__global__ __launch_bounds__(256) void main_k(
    const int* __restrict__ msg, const unsigned char* __restrict__ W1f8,
    const float* __restrict__ b1,
    const unsigned short* __restrict__ WtH, const unsigned short* __restrict__ WtL,
    const float* __restrict__ b2, const float* __restrict__ b3,
    const float* __restrict__ b4, float* __restrict__ out)
{
    const int tid = threadIdx.x, lane = tid & 63, w = tid >> 6;
    const int quad = lane >> 4, l15 = lane & 15;
    const int r0 = blockIdx.x * 16;

    __shared__ int smsg[16 * NPOS];              // 5 KB
    __shared__ float P[2][16][HID];              // 16 KB partial sums
    __shared__ unsigned short Xh[16 * XS];       // 4.25 KB
    __shared__ unsigned short Xl[16 * XS];       // 4.25 KB

    for (int k = tid; k < 16 * NPOS; k += 256)
        smsg[k] = msg[r0 * NPOS + k];
    __syncthreads();

    // ---- gather: wave handles 8 rows x 40 positions; fp8 row=128B, 16B/lane x 8 lanes
    {
        const int half = w >> 1;                     // position half
        const int rw   = ((w & 1) << 3) + (lane >> 3);   // block-local row 0..15
        const int co   = (lane & 7) << 4;            // byte offset within row
        const int* mr  = &smsg[rw * NPOS];
        f4 A0 = {0,0,0,0}, A1 = {0,0,0,0}, A2 = {0,0,0,0}, A3 = {0,0,0,0};
        const int pend = half * 40 + 40;
        #pragma unroll 1
        for (int p0 = half * 40; p0 < pend; p0 += 8) {
            int c[8];
            #pragma unroll
            for (int u = 0; u < 8; ++u) c[u] = mr[p0 + u];
            u32x4 v[8];
            #pragma unroll
            for (int u = 0; u < 8; ++u)
                v[u] = *(const u32x4*)(W1f8 + (((p0 + u) << 15) + (c[u] << 7) + co));
            #pragma unroll
            for (int u = 0; u < 8; ++u) {
                dec4_acc(v[u].x, &A0); dec4_acc(v[u].y, &A1);
                dec4_acc(v[u].z, &A2); dec4_acc(v[u].w, &A3);
            }
        }
        float* Pp = &P[half][rw][(lane & 7) << 4];
        *(f4*)&Pp[0] = A0; *(f4*)&Pp[4] = A1; *(f4*)&Pp[8] = A2; *(f4*)&Pp[12] = A3;
    }
    __syncthreads();

    // ---- combine halves + bias + ELU + hi/lo split into Xh/Xl ----
    {
        const int m = tid >> 4, j0 = (tid & 15) << 3;
        f4 s0 = (*(const f4*)&P[0][m][j0]     + *(const f4*)&P[1][m][j0])     * 0.015625f
              + *(const f4*)&b1[j0];
        f4 s1 = (*(const f4*)&P[0][m][j0 + 4] + *(const f4*)&P[1][m][j0 + 4]) * 0.015625f
              + *(const f4*)&b1[j0 + 4];
        float xs[8] = { s0.x, s0.y, s0.z, s0.w, s1.x, s1.y, s1.z, s1.w };
        unsigned short hs[8], ls[8];
        #pragma unroll
        for (int u = 0; u < 8; ++u) {
            float y = elu(xs[u]);
            hs[u] = f2bf(y);
            ls[u] = f2bf(y - bf2f(hs[u]));
        }
        *(ushort4*)&Xh[m * XS + j0]     = make_ushort4(hs[0], hs[1], hs[2], hs[3]);
        *(ushort4*)&Xh[m * XS + j0 + 4] = make_ushort4(hs[4], hs[5], hs[6], hs[7]);
        *(ushort4*)&Xl[m * XS + j0]     = make_ushort4(ls[0], ls[1], ls[2], ls[3]);
        *(ushort4*)&Xl[m * XS + j0 + 4] = make_ushort4(ls[4], ls[5], ls[6], ls[7]);
    }
    __syncthreads();

    // ---- dense: MFMA 16x16x32, 3-pass hi/lo split (verified R8 path) ----
    const float* bs[3] = { b2, b3, b4 };
    #pragma unroll 1
    for (int L = 0; L < 3; ++L) {
        bf16x8 Ah[4], Al[4];
        #pragma unroll
        for (int kt = 0; kt < 4; ++kt) {
            const int off = l15 * XS + kt * 32 + quad * 8;
            Ah[kt] = *(const bf16x8*)&Xh[off];
            Al[kt] = *(const bf16x8*)&Xl[off];
        }
        const unsigned short* WH = WtH + L * 16384;
        const unsigned short* WL = WtL + L * 16384;
        f32x4 acc[2] = { {0,0,0,0}, {0,0,0,0} };
        #pragma unroll
        for (int nt = 0; nt < 2; ++nt) {
            #pragma unroll
            for (int kt = 0; kt < 4; ++kt) {
                const int boff = ((((w << 1) + nt) << 2) + kt) * 512 + lane * 8;
                bf16x8 Bh = *(const bf16x8*)&WH[boff];
                bf16x8 Bl = *(const bf16x8*)&WL[boff];
                acc[nt] = __builtin_amdgcn_mfma_f32_16x16x32_bf16(Ah[kt], Bh, acc[nt], 0, 0, 0);
                acc[nt] = __builtin_amdgcn_mfma_f32_16x16x32_bf16(Ah[kt], Bl, acc[nt], 0, 0, 0);
                acc[nt] = __builtin_amdgcn_mfma_f32_16x16x32_bf16(Al[kt], Bh, acc[nt], 0, 0, 0);
            }
        }
        __syncthreads();

        #pragma unroll
        for (int nt = 0; nt < 2; ++nt) {
            const int n = w * 32 + nt * 16 + l15;
            const float bias = bs[L][n];
            #pragma unroll
            for (int r = 0; r < 4; ++r) {
                const int mm = quad * 4 + r;
                const float y = elu(acc[nt][r] + bias);
                if (L < 2) {
                    unsigned short hi = f2bf(y);
                    Xh[mm * XS + n] = hi;
                    Xl[mm * XS + n] = f2bf(y - bf2f(hi));
                } else {
                    out[(r0 + mm) * HID + n] = y;
                }
            }
        }
        if (L < 2) __syncthreads();
    }
}

extern "C" void kernel_launch(void* const* d_in, const int* in_sizes, int n_in,
                              void* d_out, int out_size, void* d_ws, size_t ws_size,
                              hipStream_t stream) {
    const int*   msg = (const int*)  d_in[0];
    const float* W1  = (const float*)d_in[1];
    const float* b1  = (const float*)d_in[2];
    const float* W2  = (const float*)d_in[3];
    const float* b2  = (const float*)d_in[4];
    const float* W3  = (const float*)d_in[5];
    const float* b3  = (const float*)d_in[6];
    const float* W4  = (const float*)d_in[7];
    const float* b4  = (const float*)d_in[8];
    float* out = (float*)d_out;

    // ws layout: W1f8 (2,621,440 bytes) | WtH (49,152 us) | WtL (49,152 us)
    unsigned char*  W1f8 = (unsigned char*)d_ws;
    unsigned short* WtH  = (unsigned short*)(W1f8 + 2621440);
    unsigned short* WtL  = WtH + 49152;

    prep  <<<dim3(W1_BLOCKS + TR_BLOCKS), dim3(256), 0, stream>>>(W1, W2, W3, W4,
                                                                  (u32*)W1f8, WtH, WtL);
    main_k<<<dim3(512),                   dim3(256), 0, stream>>>(msg, W1f8, b1, WtH, WtL,
                                                                  b2, b3, b4, out);
}

// Round 10
// 96.158 us; speedup vs baseline: 1.8016x; 1.0048x over previous
//
#include <hip/hip_runtime.h>
#include <math.h>

#define HID  128
#define NPOS 80
#define XS   136   // padded LDS X stride (bf16 elems)

typedef float f4 __attribute__((ext_vector_type(4)));
typedef float f2 __attribute__((ext_vector_type(2)));
typedef unsigned int u32;
typedef u32 u32x4 __attribute__((ext_vector_type(4)));
typedef __attribute__((ext_vector_type(8))) short bf16x8;
typedef __attribute__((ext_vector_type(4))) float f32x4;

__device__ __forceinline__ float elu(float x) { return x > 0.f ? x : (expf(x) - 1.f); }
__device__ __forceinline__ unsigned short f2bf(float x) {
    u32 u = __float_as_uint(x);
    return (unsigned short)((u + 0x7fffu + ((u >> 16) & 1u)) >> 16);
}
__device__ __forceinline__ float bf2f(unsigned short h) { return __uint_as_float(((u32)h) << 16); }

// ---- fp8 e4m3fn: software RNE encode (prep-side) ----
__device__ __forceinline__ u32 f2e4m3(float x) {
    u32 u = __float_as_uint(x);
    u32 sign = (u >> 31) << 7;
    float a = fabsf(x);
    if (a >= 448.f) return sign | 0x7e;
    int e = (int)((u >> 23) & 0xff) - 127;
    if (e < -6) {
        int q = (int)rintf(a * 512.0f);
        if (q >= 8) return sign | 0x08;
        return sign | (u32)q;
    }
    u32 sig = (u & 0x7fffffu) | 0x800000u;
    u32 rs = sig + 0x7ffffu + ((sig >> 20) & 1u);
    if (rs >= 0x1000000u) { e += 1; rs >>= 1; }
    u32 m3 = (rs >> 20) & 7u;
    u32 enc = ((u32)(e + 7) << 3) | m3;
    if (enc >= 0x7fu) return sign | 0x7e;
    return sign | enc;
}

#if defined(__has_builtin)
#if __has_builtin(__builtin_amdgcn_cvt_pk_f32_fp8)
#define HW_FP8 1
#endif
#endif

#ifdef HW_FP8
__device__ __forceinline__ void dec4_acc(u32 v, f4* A) {
    f2 lo = __builtin_amdgcn_cvt_pk_f32_fp8((int)v, false);
    f2 hi = __builtin_amdgcn_cvt_pk_f32_fp8((int)v, true);
    (*A).x += lo.x; (*A).y += lo.y; (*A).z += hi.x; (*A).w += hi.y;
}
#else
__device__ __forceinline__ float dec1(u32 b) {
    int em = (int)(b & 0x7fu);
    int isn = (em >= 8) ? 1 : 0;
    int frac = (em & 7) | (isn << 3);
    int e2 = isn ? (em >> 3) : 1;
    float f = ldexpf((float)frac, e2 - 10);
    return (b & 0x80u) ? -f : f;
}
__device__ __forceinline__ void dec4_acc(u32 v, f4* A) {
    (*A).x += dec1(v & 0xff); (*A).y += dec1((v >> 8) & 0xff);
    (*A).z += dec1((v >> 16) & 0xff); (*A).w += dec1(v >> 24);
}
#endif

// ---- prep: W1 -> fp8(x64) [2560 blocks]; W2/3/4 -> B-frag order (L,w8,kt,lane) [24 blocks] ----
#define W1_BLOCKS 2560
#define TR_BLOCKS 24
__global__ __launch_bounds__(256) void prep(
    const float* __restrict__ W1, const float* __restrict__ W2,
    const float* __restrict__ W3, const float* __restrict__ W4,
    u32* __restrict__ W1f8,
    unsigned short* __restrict__ WtH, unsigned short* __restrict__ WtL)
{
    int b = blockIdx.x;
    if (b < W1_BLOCKS) {
        int i = b * 256 + threadIdx.x;
        f4 f = ((const f4*)W1)[i];
        u32 pk = f2e4m3(f.x * 64.f)
               | (f2e4m3(f.y * 64.f) << 8)
               | (f2e4m3(f.z * 64.f) << 16)
               | (f2e4m3(f.w * 64.f) << 24);
        W1f8[i] = pk;
    } else {
        int t = (b - W1_BLOCKS) * 256 + threadIdx.x;   // 0..6143 = (L, w8, kt, lane)
        int lane = t & 63;
        int q = t >> 6;
        int kt = q & 3;  q >>= 2;
        int w  = q & 7;
        int L  = q >> 3;
        const float* W = (L == 0) ? W2 : (L == 1) ? W3 : W4;
        const int n    = w * 16 + (lane & 15);
        const int quad = lane >> 4;
        unsigned short hs[8], ls[8];
        #pragma unroll
        for (int j = 0; j < 8; ++j) {
            const int k = kt * 32 + quad * 8 + j;
            float v = W[k * HID + n];
            hs[j] = f2bf(v);
            ls[j] = f2bf(v - bf2f(hs[j]));
        }
        *(ushort4*)&WtH[t * 8]     = make_ushort4(hs[0], hs[1], hs[2], hs[3]);
        *(ushort4*)&WtH[t * 8 + 4] = make_ushort4(hs[4], hs[5], hs[6], hs[7]);
        *(ushort4*)&WtL[t * 8]     = make_ushort4(ls[0], ls[1], ls[2], ls[3]);
        *(ushort4*)&WtL[t * 8 + 4] = make_ushort4(ls[4], ls[5], ls[6], ls[7]);
    }
}

// ---- fused: fp8 gather (p-quartered, 16 waves/CU) + MFMA dense (n split over 8 waves) ----
__global__ __launch_bounds__(512, 4) void main_k(
    const int* __restrict__ msg, const unsigned char* __restrict__ W1f8,
    const float* __restrict__ b1,
    const unsigned short* __restrict__ WtH, const unsigned short* __restrict__ WtL,
    const float* __restrict__ b2, const float* __restrict__ b3,
    const float* __restrict__ b4, float* __restrict__ out)
{
    const int tid = threadIdx.x, lane = tid & 63, w = tid >> 6;   // w: 0..7
    const int quad = lane >> 4, l15 = lane & 15;
    const int r0 = blockIdx.x * 16;

    __shared__ int smsg[16 * NPOS];              // 5 KB
    __shared__ float P[4][16][HID];              // 32 KB partial sums
    __shared__ unsigned short Xh[16 * XS];       // 4.25 KB
    __shared__ unsigned short Xl[16 * XS];       // 4.25 KB

    for (int k = tid; k < 16 * NPOS; k += 512)
        smsg[k] = msg[r0 * NPOS + k];
    __syncthreads();

    // ---- gather: wave = (p-quarter, row-octet); 8 rows x 20 positions per wave ----
    {
        const int qtr = w >> 1;                          // position quarter (20 pos)
        const int rw  = ((w & 1) << 3) + (lane >> 3);    // block-local row 0..15
        const int co  = (lane & 7) << 4;                 // byte offset in 128B row
        const int* mr = &smsg[rw * NPOS];
        const int pbase = qtr * 20;
        f4 A0 = {0,0,0,0}, A1 = {0,0,0,0}, A2 = {0,0,0,0}, A3 = {0,0,0,0};
        #pragma unroll
        for (int h = 0; h < 2; ++h) {
            int c[10];
            #pragma unroll
            for (int u = 0; u < 10; ++u) c[u] = mr[pbase + h * 10 + u];
            u32x4 v[10];
            #pragma unroll
            for (int u = 0; u < 10; ++u)
                v[u] = *(const u32x4*)(W1f8 + (((pbase + h * 10 + u) << 15) + (c[u] << 7) + co));
            #pragma unroll
            for (int u = 0; u < 10; ++u) {
                dec4_acc(v[u].x, &A0); dec4_acc(v[u].y, &A1);
                dec4_acc(v[u].z, &A2); dec4_acc(v[u].w, &A3);
            }
        }
        float* Pp = &P[qtr][rw][(lane & 7) << 4];
        *(f4*)&Pp[0] = A0; *(f4*)&Pp[4] = A1; *(f4*)&Pp[8] = A2; *(f4*)&Pp[12] = A3;
    }
    __syncthreads();

    // ---- combine quarters + bias + ELU + hi/lo split ----
    {
        const int m = tid >> 5, j0 = (tid & 31) << 2;
        f4 s = (*(const f4*)&P[0][m][j0] + *(const f4*)&P[1][m][j0]
              + *(const f4*)&P[2][m][j0] + *(const f4*)&P[3][m][j0]) * 0.015625f
              + *(const f4*)&b1[j0];
        float ys[4] = { elu(s.x), elu(s.y), elu(s.z), elu(s.w) };
        unsigned short hs[4], ls[4];
        #pragma unroll
        for (int u = 0; u < 4; ++u) {
            hs[u] = f2bf(ys[u]);
            ls[u] = f2bf(ys[u] - bf2f(hs[u]));
        }
        *(ushort4*)&Xh[m * XS + j0] = make_ushort4(hs[0], hs[1], hs[2], hs[3]);
        *(ushort4*)&Xl[m * XS + j0] = make_ushort4(ls[0], ls[1], ls[2], ls[3]);
    }
    __syncthreads();

    // ---- dense: MFMA 16x16x32, 3-pass hi/lo; wave w owns n-columns [16w,16w+16) ----
    const float* bs[3] = { b2, b3, b4 };
    #pragma unroll 1
    for (int L = 0; L < 3; ++L) {
        bf16x8 Ah[4], Al[4];
        #pragma unroll
        for (int kt = 0; kt < 4; ++kt) {
            const int off = l15 * XS + kt * 32 + quad * 8;
            Ah[kt] = *(const bf16x8*)&Xh[off];
            Al[kt] = *(const bf16x8*)&Xl[off];
        }
        const unsigned short* WH = WtH + L * 16384;
        const unsigned short* WL = WtL + L * 16384;
        f32x4 acc = {0, 0, 0, 0};
        #pragma unroll
        for (int kt = 0; kt < 4; ++kt) {
            const int boff = (w * 4 + kt) * 512 + lane * 8;      // contiguous 1KB/wave
            bf16x8 Bh = *(const bf16x8*)&WH[boff];
            bf16x8 Bl = *(const bf16x8*)&WL[boff];
            acc = __builtin_amdgcn_mfma_f32_16x16x32_bf16(Ah[kt], Bh, acc, 0, 0, 0);
            acc = __builtin_amdgcn_mfma_f32_16x16x32_bf16(Ah[kt], Bl, acc, 0, 0, 0);
            acc = __builtin_amdgcn_mfma_f32_16x16x32_bf16(Al[kt], Bh, acc, 0, 0, 0);
        }
        __syncthreads();   // A-frag reads retired before X overwrite

        const int n = w * 16 + l15;
        const float bias = bs[L][n];
        #pragma unroll
        for (int r = 0; r < 4; ++r) {
            const int mm = quad * 4 + r;              // C layout: col=l15, row=quad*4+reg
            const float y = elu(acc[r] + bias);
            if (L < 2) {
                unsigned short hi = f2bf(y);
                Xh[mm * XS + n] = hi;
                Xl[mm * XS + n] = f2bf(y - bf2f(hi));
            } else {
                out[(r0 + mm) * HID + n] = y;
            }
        }
        if (L < 2) __syncthreads();
    }
}

extern "C" void kernel_launch(void* const* d_in, const int* in_sizes, int n_in,
                              void* d_out, int out_size, void* d_ws, size_t ws_size,
                              hipStream_t stream) {
    const int*   msg = (const int*)  d_in[0];
    const float* W1  = (const float*)d_in[1];
    const float* b1  = (const float*)d_in[2];
    const float* W2  = (const float*)d_in[3];
    const float* b2  = (const float*)d_in[4];
    const float* W3  = (const float*)d_in[5];
    const float* b3  = (const float*)d_in[6];
    const float* W4  = (const float*)d_in[7];
    const float* b4  = (const float*)d_in[8];
    float* out = (float*)d_out;

    // ws layout: W1f8 (2,621,440 bytes) | WtH (49,152 us) | WtL (49,152 us)
    unsigned char*  W1f8 = (unsigned char*)d_ws;
    unsigned short* WtH  = (unsigned short*)(W1f8 + 2621440);
    unsigned short* WtL  = WtH + 49152;

    prep  <<<dim3(W1_BLOCKS + TR_BLOCKS), dim3(256), 0, stream>>>(W1, W2, W3, W4,
                                                                  (u32*)W1f8, WtH, WtL);
    main_k<<<dim3(512),                   dim3(512), 0, stream>>>(msg, W1f8, b1, WtH, WtL,
                                                                  b2, b3, b4, out);
}